// Round 2
// baseline (200.293 us; speedup 1.0000x reference)
//
#include <hip/hip_runtime.h>
#include <stdint.h>
#include <math.h>

// ============================================================================
// Bit-exact re-implementation of the JAX (XLA:CPU) reference sampler.
//
// RNG mode: jax_threefry_partitionable = True.
//   split(key, n)[i]      = threefry2x32(key, (0, i))          (both words)
//   random_bits32 elem i  = v0 ^ v1 of threefry2x32(key, (0, i))
//
// Math library: XLA:CPU rewrites ALL f32 log/exp calls (scalar included) to
// the Cephes/Pommier GenerateVF32Log/Exp bodies -> every log/exp here is the
// Cephes port. log1p goes through XLA EmitLog1p (select + Cephes log).
// ============================================================================

__device__ __forceinline__ uint2 tf2(uint2 k, uint32_t c0, uint32_t c1) {
  uint32_t ks0 = k.x, ks1 = k.y, ks2 = k.x ^ k.y ^ 0x1BD11BDAu;
  uint32_t x0 = c0 + ks0, x1 = c1 + ks1;
#define TFR(r) { x0 += x1; x1 = (x1 << r) | (x1 >> (32 - r)); x1 ^= x0; }
  TFR(13) TFR(15) TFR(26) TFR(6)   x0 += ks1; x1 += ks2 + 1u;
  TFR(17) TFR(29) TFR(16) TFR(24)  x0 += ks2; x1 += ks0 + 2u;
  TFR(13) TFR(15) TFR(26) TFR(6)   x0 += ks0; x1 += ks1 + 3u;
  TFR(17) TFR(29) TFR(16) TFR(24)  x0 += ks1; x1 += ks2 + 4u;
  TFR(13) TFR(15) TFR(26) TFR(6)   x0 += ks2; x1 += ks0 + 5u;
#undef TFR
  return make_uint2(x0, x1);
}

__device__ __forceinline__ uint2 foldkey(uint2 k, uint32_t i) { return tf2(k, 0u, i); }
__device__ __forceinline__ uint32_t xbits(uint2 k, uint32_t i) {
  uint2 r = tf2(k, 0u, i);
  return r.x ^ r.y;
}

// uniform [0,1): (bits>>9)|0x3f800000 bitcast, minus 1  (exact ops)
__device__ __forceinline__ float u01_from_bits(uint32_t bits) {
  return __fsub_rn(__uint_as_float((bits >> 9) | 0x3f800000u), 1.0f);
}

// ---------------------------------------------------------------------------
// XLA:CPU f32 log (GenerateVF32Log — Cephes/Pommier log_ps, plain rn ops).
// Used for EVERY f32 log in the program (XLA rewrites scalar calls too).
// ---------------------------------------------------------------------------
__device__ float cephes_logf(float xin) {
  if (xin == 0.0f) return -__builtin_inff();
  if (xin < 0.0f)  return __builtin_nanf("");
  float x = fmaxf(xin, 1.17549435e-38f);
  uint32_t xb = __float_as_uint(x);
  int e_int = (int)(xb >> 23) - 0x7f;
  x = __uint_as_float((xb & 0x807fffffu) | 0x3f000000u);  // mantissa in [0.5,1)
  float e = __fadd_rn((float)e_int, 1.0f);
  bool mlt = x < 0.707106781186547524f;    // f32 literal compare
  float tmp = mlt ? x : 0.0f;
  x = __fsub_rn(x, 1.0f);
  e = __fsub_rn(e, mlt ? 1.0f : 0.0f);
  x = __fadd_rn(x, tmp);
  float z = __fmul_rn(x, x);
  float y = 7.0376836292e-2f;
  y = __fadd_rn(__fmul_rn(y, x), -1.1514610310e-1f);
  y = __fadd_rn(__fmul_rn(y, x),  1.1676998740e-1f);
  y = __fadd_rn(__fmul_rn(y, x), -1.2420140846e-1f);
  y = __fadd_rn(__fmul_rn(y, x),  1.4249322787e-1f);
  y = __fadd_rn(__fmul_rn(y, x), -1.6668057665e-1f);
  y = __fadd_rn(__fmul_rn(y, x),  2.0000714765e-1f);
  y = __fadd_rn(__fmul_rn(y, x), -2.4999993993e-1f);
  y = __fadd_rn(__fmul_rn(y, x),  3.3333331174e-1f);
  y = __fmul_rn(y, x);
  y = __fmul_rn(y, z);
  y = __fadd_rn(y, __fmul_rn(e, -2.12194440e-4f));
  y = __fsub_rn(y, __fmul_rn(z, 0.5f));
  x = __fadd_rn(x, y);
  x = __fadd_rn(x, __fmul_rn(e, 0.693359375f));
  return x;
}

// ---------------------------------------------------------------------------
// XLA:CPU f32 exp (GenerateVF32Exp — Cephes/Pommier exp_ps, plain rn ops).
// ---------------------------------------------------------------------------
__device__ float cephes_expf(float xin) {
  float x = fminf(xin, 88.3762626647950f);
  x = fmaxf(x, -88.3762626647949f);
  float fx = __fadd_rn(__fmul_rn(x, 1.44269504088896341f), 0.5f);
  fx = floorf(fx);
  float tmp = __fmul_rn(fx, 0.693359375f);
  float z2  = __fmul_rn(fx, -2.12194440e-4f);
  x = __fsub_rn(x, tmp);
  x = __fsub_rn(x, z2);
  float z = __fmul_rn(x, x);
  float y = 1.9875691500e-4f;
  y = __fadd_rn(__fmul_rn(y, x), 1.3981999507e-3f);
  y = __fadd_rn(__fmul_rn(y, x), 8.3334519073e-3f);
  y = __fadd_rn(__fmul_rn(y, x), 4.1665795894e-2f);
  y = __fadd_rn(__fmul_rn(y, x), 1.6666665459e-1f);
  y = __fadd_rn(__fmul_rn(y, x), 5.0000001201e-1f);
  y = __fadd_rn(__fmul_rn(y, z), x);
  y = __fadd_rn(y, 1.0f);
  int n = (int)fx;
  float p2n = __uint_as_float((uint32_t)(n + 0x7f) << 23);
  return __fmul_rn(y, p2n);
}

// XLA EmitLog1p: |x| < 1e-4 ? (x*(-0.5)+1)*x : log(x+1)   (log = Cephes)
__device__ __forceinline__ float xla_log1p(float x) {
  float for_small = __fmul_rn(__fadd_rn(__fmul_rn(-0.5f, x), 1.0f), x);
  float for_large = cephes_logf(__fadd_rn(x, 1.0f));
  return (fabsf(x) < 1e-4f) ? for_small : for_large;
}

// ---------------------------------------------------------------------------
// XLA ErfInv f32 expansion (both branches computed, selected — matches HLO).
// ---------------------------------------------------------------------------
__device__ float xla_erfinv_f32(float x) {
  float m = __fmul_rn(x, x);
  float w = -xla_log1p(-m);
  float ws = __fsub_rn(w, 2.5f);
  float wb = __fsub_rn(__fsqrt_rn(w), 3.0f);
  float ps = 2.81022636e-08f;
  ps = __fadd_rn(__fmul_rn(ps, ws), 3.43273939e-07f);
  ps = __fadd_rn(__fmul_rn(ps, ws), -3.5233877e-06f);
  ps = __fadd_rn(__fmul_rn(ps, ws), -4.39150654e-06f);
  ps = __fadd_rn(__fmul_rn(ps, ws), 0.00021858087f);
  ps = __fadd_rn(__fmul_rn(ps, ws), -0.00125372503f);
  ps = __fadd_rn(__fmul_rn(ps, ws), -0.00417768164f);
  ps = __fadd_rn(__fmul_rn(ps, ws), 0.246640727f);
  ps = __fadd_rn(__fmul_rn(ps, ws), 1.50140941f);
  float pb = -0.000200214257f;
  pb = __fadd_rn(__fmul_rn(pb, wb), 0.000100950558f);
  pb = __fadd_rn(__fmul_rn(pb, wb), 0.00134934322f);
  pb = __fadd_rn(__fmul_rn(pb, wb), -0.00367342844f);
  pb = __fadd_rn(__fmul_rn(pb, wb), 0.00573950773f);
  pb = __fadd_rn(__fmul_rn(pb, wb), -0.0076224613f);
  pb = __fadd_rn(__fmul_rn(pb, wb), 0.00943887047f);
  pb = __fadd_rn(__fmul_rn(pb, wb), 1.00167406f);
  pb = __fadd_rn(__fmul_rn(pb, wb), 2.83297682f);
  float p = (w < 5.0f) ? ps : pb;
  return __fmul_rn(p, x);
}

// jax.random.normal: uniform in [nextafter(-1,0), 1) then sqrt(2)*erfinv
__device__ __forceinline__ float normal_from_bits(uint32_t bits) {
  float f = u01_from_bits(bits);
  float u = __fadd_rn(__fmul_rn(f, 2.0f), -0.99999994f);  // (1-(-0.99999994)) rn-> 2.0
  u = fmaxf(-0.99999994f, u);
  return __fmul_rn(1.4142135623730951f, xla_erfinv_f32(u));
}

// ---------------------------------------------------------------------------
// jax.random loggamma(alpha=255.5) for one element key K (log_space=True).
// Marsaglia–Tsang; key chain exactly as jax._src.random._gamma_one.
// All logs = Cephes (XLA rewrites scalar logf too).
// ---------------------------------------------------------------------------
__device__ float loggamma2555(uint2 K) {
  const float ONE3 = 1.0f / 3.0f;
  const float d_g  = __fsub_rn(255.5f, ONE3);                 // d = alpha - 1/3
  const float c_g  = __fdiv_rn(ONE3, __fsqrt_rn(d_g));        // c = (1/3)/sqrt(d)

  // key, subkey = split(key); u_boost = uniform(subkey)  [value unused: alpha>=1]
  uint2 key = foldkey(K, 0u);

  float X = 0.0f, V = 1.0f, U = 2.0f;
  for (;;) {
    // cond: U >= 1 - 0.0331*(X*X)  &&  log(U) >= 0.5*X + d*((1-V) + log(V))
    float sq = __fsub_rn(1.0f, __fmul_rn(0.0331f, __fmul_rn(X, X)));
    bool c1 = (U >= sq);
    bool c2 = false;
    if (c1) {
      float rhs = __fadd_rn(__fmul_rn(X, 0.5f),
                            __fmul_rn(d_g, __fadd_rn(__fsub_rn(1.0f, V),
                                                     cephes_logf(V))));
      c2 = (cephes_logf(U) >= rhs);
    }
    if (!(c1 && c2)) break;   // accept -> exit

    // body: key, x_key, U_key = split(key, 3)
    uint2 nk   = foldkey(key, 0u);
    uint2 xkey = foldkey(key, 1u);
    uint2 Ukey = foldkey(key, 2u);
    key = nk;
    float x, v;
    do {
      uint2 nxk  = foldkey(xkey, 0u);
      uint2 nsub = foldkey(xkey, 1u);
      xkey = nxk;
      x = normal_from_bits(xbits(nsub, 0u));
      v = __fadd_rn(1.0f, __fmul_rn(x, c_g));
    } while (v <= 0.0f);
    X = __fmul_rn(x, x);
    V = __fmul_rn(__fmul_rn(v, v), v);
    U = u01_from_bits(xbits(Ukey, 0u));
  }
  // log(d) + log(V) + log_boost(=0 since alpha>=1)
  return __fadd_rn(__fadd_rn(cephes_logf(d_g), cephes_logf(V)), 0.0f);
}

__device__ __forceinline__ float wave_reduce64(float v) {
  for (int off = 32; off >= 1; off >>= 1) v += __shfl_xor(v, off, 64);
  return v;
}

// ============================================================================
// One block per batch row.  Wave 0 lanes 0..49 compute the 50 scan steps in
// parallel (first-accept-wins); all 256 threads handle 2 columns each.
// ============================================================================
__global__ void __launch_bounds__(256)
vmf_kernel(const float* __restrict__ loc, const float* __restrict__ scale,
           float* __restrict__ out, int B) {
  const int r = blockIdx.x;
  if (r >= B) return;
  const int t = threadIdx.x;
  const int lane = t & 63, wid = t >> 6;

  __shared__ float s_w;
  __shared__ float s_part[3][4];

  const uint2 key42 = make_uint2(0u, 42u);   // jax.random.key(42)

  // ------------------ w-path (wave 0) ------------------
  if (wid == 0) {
    float w_val = 0.0f;
    bool acc = false;
    if (lane < 50) {
      const float kappa = scale[r];
      const float c_ = __fsqrt_rn(__fadd_rn(__fmul_rn(4.0f, __fmul_rn(kappa, kappa)),
                                            261121.0f));
      // s = clip(kappa-10,0,1) == 1.0 for kappa in [20,80)  =>  b = b_app exactly
      const float b_app  = __fdiv_rn(511.0f, __fmul_rn(4.0f, kappa));
      const float b_true = __fdiv_rn(__fadd_rn(__fmul_rn(-2.0f, kappa), c_), 511.0f);
      float s_ = __fsub_rn(kappa, 10.0f);
      s_ = fminf(fmaxf(s_, 0.0f), 1.0f);
      const float b = __fadd_rn(__fmul_rn(b_app, s_),
                                __fmul_rn(b_true, __fsub_rn(1.0f, s_)));
      const float a = __fdiv_rn(__fadd_rn(__fadd_rn(511.0f, __fmul_rn(2.0f, kappa)), c_),
                                4.0f);
      const float log511 = cephes_logf(511.0f);   // jnp.log(511.0) -> XLA Cephes
      const float dconst = __fsub_rn(
          __fdiv_rn(__fmul_rn(__fmul_rn(4.0f, a), b), __fadd_rn(1.0f, b)),
          __fmul_rn(511.0f, log511));

      // kw,kv = split(key42); keys = split(kw,50); this lane handles step i=lane
      uint2 kw = foldkey(key42, 0u);
      uint2 ki = foldkey(kw, (uint32_t)lane);
      uint2 kb = foldkey(ki, 0u);              // kb,ku = split(k)
      uint2 ku = foldkey(ki, 1u);
      uint2 ka = foldkey(kb, 0u);              // key_a,key_b = split(kb)
      uint2 kB = foldkey(kb, 1u);
      // per-element gamma keys: split(key_a, 32768)[r]
      float lga = loggamma2555(foldkey(ka, (uint32_t)r));
      float lgb = loggamma2555(foldkey(kB, (uint32_t)r));
      float lm  = fmaxf(lga, lgb);
      float gas = cephes_expf(__fsub_rn(lga, lm));
      float gbs = cephes_expf(__fsub_rn(lgb, lm));
      float e_  = __fdiv_rn(gas, __fadd_rn(gas, gbs));
      float uu  = u01_from_bits(xbits(ku, (uint32_t)r));

      float denom = __fsub_rn(1.0f, __fmul_rn(__fsub_rn(1.0f, b), e_));
      w_val = __fdiv_rn(__fsub_rn(1.0f, __fmul_rn(__fadd_rn(1.0f, b), e_)), denom);
      float tt  = __fdiv_rn(__fmul_rn(__fmul_rn(2.0f, a), b), denom);
      float lhs = __fadd_rn(__fsub_rn(__fmul_rn(511.0f, cephes_logf(tt)), tt), dconst);
      acc = (lhs > cephes_logf(uu));
    }
    unsigned long long am = __ballot(acc ? 1 : 0);
    float wsel = 0.0f;
    if (am) {
      int fl = __ffsll(am) - 1;     // earliest accepting step wins
      wsel = __shfl(w_val, fl, 64);
    }
    if (lane == 0) s_w = wsel;
  }
  __syncthreads();
  const float w = s_w;

  // ------------------ tangential part + Householder ------------------
  uint2 kv = foldkey(key42, 1u);
  const int cA = t, cB = t + 256;
  const float lA = loc[(size_t)r * 512 + cA];
  const float lB = loc[(size_t)r * 512 + cB];
  const float uhA = (cA == 0) ? __fsub_rn(1.0f, lA) : __fsub_rn(0.0f, lA);
  const float uhB = __fsub_rn(0.0f, lB);
  float vfA = 0.0f;
  if (cA >= 1) vfA = normal_from_bits(xbits(kv, (uint32_t)(r * 512 + cA)));
  float vfB = normal_from_bits(xbits(kv, (uint32_t)(r * 512 + cB)));

  float rv = wave_reduce64(vfA * vfA + vfB * vfB);
  float ru = wave_reduce64(uhA * uhA + uhB * uhB);
  if (lane == 0) { s_part[0][wid] = rv; s_part[1][wid] = ru; }
  __syncthreads();
  const float SV = s_part[0][0] + s_part[0][1] + s_part[0][2] + s_part[0][3];
  const float SU = s_part[1][0] + s_part[1][1] + s_part[1][2] + s_part[1][3];

  const float normv = __fsqrt_rn(SV);
  const float normu = __fadd_rn(__fsqrt_rn(SU), 1e-5f);
  const float fac = __fsqrt_rn(fmaxf(1e-10f, __fsub_rn(1.0f, __fmul_rn(w, w))));

  const float xA = (cA == 0) ? w : __fmul_rn(fac, __fdiv_rn(vfA, normv));
  const float xB = __fmul_rn(fac, __fdiv_rn(vfB, normv));
  const float uuA = __fdiv_rn(uhA, normu);
  const float uuB = __fdiv_rn(uhB, normu);

  float rd = wave_reduce64(xA * uuA + xB * uuB);
  if (lane == 0) s_part[2][wid] = rd;
  __syncthreads();
  const float DOT = s_part[2][0] + s_part[2][1] + s_part[2][2] + s_part[2][3];
  const float s2 = __fmul_rn(2.0f, DOT);

  out[(size_t)r * 512 + cA] = __fsub_rn(xA, __fmul_rn(s2, uuA));
  out[(size_t)r * 512 + cB] = __fsub_rn(xB, __fmul_rn(s2, uuB));
}

extern "C" void kernel_launch(void* const* d_in, const int* in_sizes, int n_in,
                              void* d_out, int out_size, void* d_ws, size_t ws_size,
                              hipStream_t stream) {
  const float* loc   = (const float*)d_in[0];
  const float* scale = (const float*)d_in[1];
  float* out = (float*)d_out;
  const int B = in_sizes[1];     // scale is (B,1); loc is (B,512)
  hipLaunchKernelGGL(vmf_kernel, dim3(B), dim3(256), 0, stream, loc, scale, out, B);
}

// Round 3
// 72.515 us; speedup vs baseline: 2.7621x; 2.7621x over previous
//
#include <hip/hip_runtime.h>
#include <stdint.h>
#include <math.h>

// ============================================================================
// Bit-exact re-implementation of the JAX (XLA:CPU) reference sampler.
//
// RNG mode: jax_threefry_partitionable = True.
//   split(key, n)[i]      = threefry2x32(key, (0, i))          (both words)
//   random_bits32 elem i  = v0 ^ v1 of threefry2x32(key, (0, i))
//
// Math library: XLA:CPU rewrites ALL f32 log/exp calls (scalar included) to
// the Cephes/Pommier GenerateVF32Log/Exp bodies. log1p via XLA EmitLog1p.
//
// Structure (round 3): two kernels.
//   K1: one lane-PAIR per row, serial Wood rejection with EARLY EXIT at the
//       first accept (reference's scan keeps only the first accept; later
//       steps are dead values, so skipping them is bit-exact). w -> out[r*512].
//   K2: 256 thr/row tangential + Householder; reads w from out[r*512] before
//       overwriting the row (in-block barriers order read-before-write).
// ============================================================================

__device__ __forceinline__ uint2 tf2(uint2 k, uint32_t c0, uint32_t c1) {
  uint32_t ks0 = k.x, ks1 = k.y, ks2 = k.x ^ k.y ^ 0x1BD11BDAu;
  uint32_t x0 = c0 + ks0, x1 = c1 + ks1;
#define TFR(r) { x0 += x1; x1 = (x1 << r) | (x1 >> (32 - r)); x1 ^= x0; }
  TFR(13) TFR(15) TFR(26) TFR(6)   x0 += ks1; x1 += ks2 + 1u;
  TFR(17) TFR(29) TFR(16) TFR(24)  x0 += ks2; x1 += ks0 + 2u;
  TFR(13) TFR(15) TFR(26) TFR(6)   x0 += ks0; x1 += ks1 + 3u;
  TFR(17) TFR(29) TFR(16) TFR(24)  x0 += ks1; x1 += ks2 + 4u;
  TFR(13) TFR(15) TFR(26) TFR(6)   x0 += ks2; x1 += ks0 + 5u;
#undef TFR
  return make_uint2(x0, x1);
}

__device__ __forceinline__ uint2 foldkey(uint2 k, uint32_t i) { return tf2(k, 0u, i); }
__device__ __forceinline__ uint32_t xbits(uint2 k, uint32_t i) {
  uint2 r = tf2(k, 0u, i);
  return r.x ^ r.y;
}

__device__ __forceinline__ float u01_from_bits(uint32_t bits) {
  return __fsub_rn(__uint_as_float((bits >> 9) | 0x3f800000u), 1.0f);
}

// ---------------------------------------------------------------------------
// XLA:CPU f32 log (GenerateVF32Log — Cephes/Pommier log_ps, plain rn ops).
// ---------------------------------------------------------------------------
__device__ float cephes_logf(float xin) {
  if (xin == 0.0f) return -__builtin_inff();
  if (xin < 0.0f)  return __builtin_nanf("");
  float x = fmaxf(xin, 1.17549435e-38f);
  uint32_t xb = __float_as_uint(x);
  int e_int = (int)(xb >> 23) - 0x7f;
  x = __uint_as_float((xb & 0x807fffffu) | 0x3f000000u);  // mantissa in [0.5,1)
  float e = __fadd_rn((float)e_int, 1.0f);
  bool mlt = x < 0.707106781186547524f;
  float tmp = mlt ? x : 0.0f;
  x = __fsub_rn(x, 1.0f);
  e = __fsub_rn(e, mlt ? 1.0f : 0.0f);
  x = __fadd_rn(x, tmp);
  float z = __fmul_rn(x, x);
  float y = 7.0376836292e-2f;
  y = __fadd_rn(__fmul_rn(y, x), -1.1514610310e-1f);
  y = __fadd_rn(__fmul_rn(y, x),  1.1676998740e-1f);
  y = __fadd_rn(__fmul_rn(y, x), -1.2420140846e-1f);
  y = __fadd_rn(__fmul_rn(y, x),  1.4249322787e-1f);
  y = __fadd_rn(__fmul_rn(y, x), -1.6668057665e-1f);
  y = __fadd_rn(__fmul_rn(y, x),  2.0000714765e-1f);
  y = __fadd_rn(__fmul_rn(y, x), -2.4999993993e-1f);
  y = __fadd_rn(__fmul_rn(y, x),  3.3333331174e-1f);
  y = __fmul_rn(y, x);
  y = __fmul_rn(y, z);
  y = __fadd_rn(y, __fmul_rn(e, -2.12194440e-4f));
  y = __fsub_rn(y, __fmul_rn(z, 0.5f));
  x = __fadd_rn(x, y);
  x = __fadd_rn(x, __fmul_rn(e, 0.693359375f));
  return x;
}

// ---------------------------------------------------------------------------
// XLA:CPU f32 exp (GenerateVF32Exp — Cephes/Pommier exp_ps, plain rn ops).
// ---------------------------------------------------------------------------
__device__ float cephes_expf(float xin) {
  float x = fminf(xin, 88.3762626647950f);
  x = fmaxf(x, -88.3762626647949f);
  float fx = __fadd_rn(__fmul_rn(x, 1.44269504088896341f), 0.5f);
  fx = floorf(fx);
  float tmp = __fmul_rn(fx, 0.693359375f);
  float z2  = __fmul_rn(fx, -2.12194440e-4f);
  x = __fsub_rn(x, tmp);
  x = __fsub_rn(x, z2);
  float z = __fmul_rn(x, x);
  float y = 1.9875691500e-4f;
  y = __fadd_rn(__fmul_rn(y, x), 1.3981999507e-3f);
  y = __fadd_rn(__fmul_rn(y, x), 8.3334519073e-3f);
  y = __fadd_rn(__fmul_rn(y, x), 4.1665795894e-2f);
  y = __fadd_rn(__fmul_rn(y, x), 1.6666665459e-1f);
  y = __fadd_rn(__fmul_rn(y, x), 5.0000001201e-1f);
  y = __fadd_rn(__fmul_rn(y, z), x);
  y = __fadd_rn(y, 1.0f);
  int n = (int)fx;
  float p2n = __uint_as_float((uint32_t)(n + 0x7f) << 23);
  return __fmul_rn(y, p2n);
}

// XLA EmitLog1p: |x| < 1e-4 ? (x*(-0.5)+1)*x : log(x+1)
__device__ __forceinline__ float xla_log1p(float x) {
  float for_small = __fmul_rn(__fadd_rn(__fmul_rn(-0.5f, x), 1.0f), x);
  float for_large = cephes_logf(__fadd_rn(x, 1.0f));
  return (fabsf(x) < 1e-4f) ? for_small : for_large;
}

// ---------------------------------------------------------------------------
// XLA ErfInv f32. pb branch (w>=5, |u| > 0.99665 — ~0.3%/lane) is skipped
// when no lane in the wave needs it; selected value identical either way.
// ---------------------------------------------------------------------------
__device__ float xla_erfinv_f32(float x) {
  float m = __fmul_rn(x, x);
  float w = -xla_log1p(-m);
  float ws = __fsub_rn(w, 2.5f);
  float ps = 2.81022636e-08f;
  ps = __fadd_rn(__fmul_rn(ps, ws), 3.43273939e-07f);
  ps = __fadd_rn(__fmul_rn(ps, ws), -3.5233877e-06f);
  ps = __fadd_rn(__fmul_rn(ps, ws), -4.39150654e-06f);
  ps = __fadd_rn(__fmul_rn(ps, ws), 0.00021858087f);
  ps = __fadd_rn(__fmul_rn(ps, ws), -0.00125372503f);
  ps = __fadd_rn(__fmul_rn(ps, ws), -0.00417768164f);
  ps = __fadd_rn(__fmul_rn(ps, ws), 0.246640727f);
  ps = __fadd_rn(__fmul_rn(ps, ws), 1.50140941f);
  float p = ps;
  if (__ballot(w >= 5.0f) != 0ull) {            // wave-uniform branch
    float wb = __fsub_rn(__fsqrt_rn(w), 3.0f);
    float pb = -0.000200214257f;
    pb = __fadd_rn(__fmul_rn(pb, wb), 0.000100950558f);
    pb = __fadd_rn(__fmul_rn(pb, wb), 0.00134934322f);
    pb = __fadd_rn(__fmul_rn(pb, wb), -0.00367342844f);
    pb = __fadd_rn(__fmul_rn(pb, wb), 0.00573950773f);
    pb = __fadd_rn(__fmul_rn(pb, wb), -0.0076224613f);
    pb = __fadd_rn(__fmul_rn(pb, wb), 0.00943887047f);
    pb = __fadd_rn(__fmul_rn(pb, wb), 1.00167406f);
    pb = __fadd_rn(__fmul_rn(pb, wb), 2.83297682f);
    p = (w < 5.0f) ? ps : pb;
  }
  return __fmul_rn(p, x);
}

__device__ __forceinline__ float normal_from_bits(uint32_t bits) {
  float f = u01_from_bits(bits);
  float u = __fadd_rn(__fmul_rn(f, 2.0f), -0.99999994f);
  u = fmaxf(-0.99999994f, u);
  return __fmul_rn(1.4142135623730951f, xla_erfinv_f32(u));
}

// ---------------------------------------------------------------------------
// jax.random loggamma(alpha=255.5), key chain per jax._src.random._gamma_one.
// ---------------------------------------------------------------------------
__device__ float loggamma2555(uint2 K) {
  const float ONE3 = 1.0f / 3.0f;
  const float d_g  = __fsub_rn(255.5f, ONE3);
  const float c_g  = __fdiv_rn(ONE3, __fsqrt_rn(d_g));

  uint2 key = foldkey(K, 0u);   // key, subkey = split(key); u_boost unused

  float X = 0.0f, V = 1.0f, U = 2.0f;
  for (;;) {
    float sq = __fsub_rn(1.0f, __fmul_rn(0.0331f, __fmul_rn(X, X)));
    bool c1 = (U >= sq);
    bool c2 = false;
    if (c1) {
      float rhs = __fadd_rn(__fmul_rn(X, 0.5f),
                            __fmul_rn(d_g, __fadd_rn(__fsub_rn(1.0f, V),
                                                     cephes_logf(V))));
      c2 = (cephes_logf(U) >= rhs);
    }
    if (!(c1 && c2)) break;

    uint2 nk   = foldkey(key, 0u);
    uint2 xkey = foldkey(key, 1u);
    uint2 Ukey = foldkey(key, 2u);
    key = nk;
    float x, v;
    do {
      uint2 nxk  = foldkey(xkey, 0u);
      uint2 nsub = foldkey(xkey, 1u);
      xkey = nxk;
      x = normal_from_bits(xbits(nsub, 0u));
      v = __fadd_rn(1.0f, __fmul_rn(x, c_g));
    } while (v <= 0.0f);
    X = __fmul_rn(x, x);
    V = __fmul_rn(__fmul_rn(v, v), v);
    U = u01_from_bits(xbits(Ukey, 0u));
  }
  return __fadd_rn(__fadd_rn(cephes_logf(d_g), cephes_logf(V)), 0.0f);
}

__device__ __forceinline__ float wave_reduce64(float v) {
  for (int off = 32; off >= 1; off >>= 1) v += __shfl_xor(v, off, 64);
  return v;
}

// ============================================================================
// K1: one lane-pair per row. parity 0 -> gamma_a, parity 1 -> gamma_b.
// Serial step loop, EARLY EXIT on first accept (both lanes of a pair compute
// the identical accept decision, so they stay converged). w -> out[r*512].
// ============================================================================
__global__ void __launch_bounds__(256)
vmf_w_kernel(const float* __restrict__ scale, float* __restrict__ out, int B) {
  const int gt = blockIdx.x * 256 + threadIdx.x;
  const int r = gt >> 1;
  const int parity = gt & 1;
  if (r >= B) return;

  const uint2 key42 = make_uint2(0u, 42u);
  const float kappa = scale[r];

  const float c_ = __fsqrt_rn(__fadd_rn(__fmul_rn(4.0f, __fmul_rn(kappa, kappa)),
                                        261121.0f));
  const float b_app  = __fdiv_rn(511.0f, __fmul_rn(4.0f, kappa));
  const float b_true = __fdiv_rn(__fadd_rn(__fmul_rn(-2.0f, kappa), c_), 511.0f);
  float s_ = __fsub_rn(kappa, 10.0f);
  s_ = fminf(fmaxf(s_, 0.0f), 1.0f);
  const float b = __fadd_rn(__fmul_rn(b_app, s_),
                            __fmul_rn(b_true, __fsub_rn(1.0f, s_)));
  const float a = __fdiv_rn(__fadd_rn(__fadd_rn(511.0f, __fmul_rn(2.0f, kappa)), c_),
                            4.0f);
  const float log511 = cephes_logf(511.0f);
  const float dconst = __fsub_rn(
      __fdiv_rn(__fmul_rn(__fmul_rn(4.0f, a), b), __fadd_rn(1.0f, b)),
      __fmul_rn(511.0f, log511));

  const uint2 kw = foldkey(key42, 0u);

  float w_val = 0.0f;
  for (int i = 0; i < 50; ++i) {
    uint2 ki = foldkey(kw, (uint32_t)i);
    uint2 kb = foldkey(ki, 0u);
    uint2 ku = foldkey(ki, 1u);
    uint2 kg = foldkey(kb, (uint32_t)parity);    // key_a (p=0) / key_b (p=1)
    float lg_self  = loggamma2555(foldkey(kg, (uint32_t)r));
    float lg_other = __shfl_xor(lg_self, 1, 64);
    float lga = parity ? lg_other : lg_self;
    float lgb = parity ? lg_self  : lg_other;
    float lm  = fmaxf(lga, lgb);
    float gas = cephes_expf(__fsub_rn(lga, lm));
    float gbs = cephes_expf(__fsub_rn(lgb, lm));
    float e_  = __fdiv_rn(gas, __fadd_rn(gas, gbs));
    float uu  = u01_from_bits(xbits(ku, (uint32_t)r));

    float denom = __fsub_rn(1.0f, __fmul_rn(__fsub_rn(1.0f, b), e_));
    float w_ = __fdiv_rn(__fsub_rn(1.0f, __fmul_rn(__fadd_rn(1.0f, b), e_)), denom);
    float tt  = __fdiv_rn(__fmul_rn(__fmul_rn(2.0f, a), b), denom);
    float lhs = __fadd_rn(__fsub_rn(__fmul_rn(511.0f, cephes_logf(tt)), tt), dconst);
    if (lhs > cephes_logf(uu)) { w_val = w_; break; }   // first accept wins
  }
  if (parity == 0) out[(size_t)r * 512] = w_val;
}

// ============================================================================
// K2: 256 threads per row; tangential normals + Householder.
// Reads w from out[r*512] (written by K1) before overwriting the row — the
// reduction barriers order all reads before any write.
// ============================================================================
__global__ void __launch_bounds__(256)
vmf_tan_kernel(const float* __restrict__ loc, float* __restrict__ out, int B) {
  const int r = blockIdx.x;
  if (r >= B) return;
  const int t = threadIdx.x;
  const int lane = t & 63, wid = t >> 6;

  __shared__ float s_part[3][4];

  const float w = out[(size_t)r * 512];          // from K1

  const uint2 key42 = make_uint2(0u, 42u);
  const uint2 kv = foldkey(key42, 1u);
  const int cA = t, cB = t + 256;
  const float lA = loc[(size_t)r * 512 + cA];
  const float lB = loc[(size_t)r * 512 + cB];
  const float uhA = (cA == 0) ? __fsub_rn(1.0f, lA) : __fsub_rn(0.0f, lA);
  const float uhB = __fsub_rn(0.0f, lB);
  float vfA = 0.0f;
  if (cA >= 1) vfA = normal_from_bits(xbits(kv, (uint32_t)(r * 512 + cA)));
  float vfB = normal_from_bits(xbits(kv, (uint32_t)(r * 512 + cB)));

  float rv = wave_reduce64(vfA * vfA + vfB * vfB);
  float ru = wave_reduce64(uhA * uhA + uhB * uhB);
  if (lane == 0) { s_part[0][wid] = rv; s_part[1][wid] = ru; }
  __syncthreads();
  const float SV = s_part[0][0] + s_part[0][1] + s_part[0][2] + s_part[0][3];
  const float SU = s_part[1][0] + s_part[1][1] + s_part[1][2] + s_part[1][3];

  const float normv = __fsqrt_rn(SV);
  const float normu = __fadd_rn(__fsqrt_rn(SU), 1e-5f);
  const float fac = __fsqrt_rn(fmaxf(1e-10f, __fsub_rn(1.0f, __fmul_rn(w, w))));

  const float xA = (cA == 0) ? w : __fmul_rn(fac, __fdiv_rn(vfA, normv));
  const float xB = __fmul_rn(fac, __fdiv_rn(vfB, normv));
  const float uuA = __fdiv_rn(uhA, normu);
  const float uuB = __fdiv_rn(uhB, normu);

  float rd = wave_reduce64(xA * uuA + xB * uuB);
  if (lane == 0) s_part[2][wid] = rd;
  __syncthreads();
  const float DOT = s_part[2][0] + s_part[2][1] + s_part[2][2] + s_part[2][3];
  const float s2 = __fmul_rn(2.0f, DOT);

  out[(size_t)r * 512 + cA] = __fsub_rn(xA, __fmul_rn(s2, uuA));
  out[(size_t)r * 512 + cB] = __fsub_rn(xB, __fmul_rn(s2, uuB));
}

extern "C" void kernel_launch(void* const* d_in, const int* in_sizes, int n_in,
                              void* d_out, int out_size, void* d_ws, size_t ws_size,
                              hipStream_t stream) {
  const float* loc   = (const float*)d_in[0];
  const float* scale = (const float*)d_in[1];
  float* out = (float*)d_out;
  const int B = in_sizes[1];     // scale is (B,1); loc is (B,512)
  const int g1 = (2 * B + 255) / 256;
  hipLaunchKernelGGL(vmf_w_kernel, dim3(g1), dim3(256), 0, stream, scale, out, B);
  hipLaunchKernelGGL(vmf_tan_kernel, dim3(B), dim3(256), 0, stream, loc, out, B);
}

// Round 4
// 59.532 us; speedup vs baseline: 3.3644x; 1.2181x over previous
//
#include <hip/hip_runtime.h>
#include <stdint.h>
#include <math.h>

// ============================================================================
// Bit-exact-where-it-matters re-implementation of the JAX (XLA:CPU) sampler.
//
// RNG mode: jax_threefry_partitionable = True.
//   split(key, n)[i]      = threefry2x32(key, (0, i))          (both words)
//   random_bits32 elem i  = v0 ^ v1 of threefry2x32(key, (0, i))
//
// K1 (w-path): FULL bit-exactness (Cephes log/exp, unfused rn ops) — the
//   rejection decisions amplify perturbations by x255/x511, so any ulp
//   deviation risks a decision flip (~0.01..0.05 output error).
// K2 (tangential): decisions-free; only needs ~1e-4 accuracy vs the 4.6e-3
//   threshold. Uses HW v_log_f32, fused fma polynomial, v_rcp division.
// ============================================================================

__device__ __forceinline__ uint2 tf2(uint2 k, uint32_t c0, uint32_t c1) {
  uint32_t ks0 = k.x, ks1 = k.y, ks2 = k.x ^ k.y ^ 0x1BD11BDAu;
  uint32_t x0 = c0 + ks0, x1 = c1 + ks1;
#define TFR(r) { x0 += x1; x1 = __builtin_rotateleft32(x1, r); x1 ^= x0; }
  TFR(13) TFR(15) TFR(26) TFR(6)   x0 += ks1; x1 += ks2 + 1u;
  TFR(17) TFR(29) TFR(16) TFR(24)  x0 += ks2; x1 += ks0 + 2u;
  TFR(13) TFR(15) TFR(26) TFR(6)   x0 += ks0; x1 += ks1 + 3u;
  TFR(17) TFR(29) TFR(16) TFR(24)  x0 += ks1; x1 += ks2 + 4u;
  TFR(13) TFR(15) TFR(26) TFR(6)   x0 += ks2; x1 += ks0 + 5u;
#undef TFR
  return make_uint2(x0, x1);
}

__device__ __forceinline__ uint2 foldkey(uint2 k, uint32_t i) { return tf2(k, 0u, i); }
__device__ __forceinline__ uint32_t xbits(uint2 k, uint32_t i) {
  uint2 r = tf2(k, 0u, i);
  return r.x ^ r.y;
}

__device__ __forceinline__ float u01_from_bits(uint32_t bits) {
  return __fsub_rn(__uint_as_float((bits >> 9) | 0x3f800000u), 1.0f);
}

// ---------------------------------------------------------------------------
// EXACT PATH (K1 only) — XLA:CPU Cephes log/exp, XLA log1p/erfinv, rn ops.
// ---------------------------------------------------------------------------
__device__ float cephes_logf(float xin) {
  if (xin == 0.0f) return -__builtin_inff();
  if (xin < 0.0f)  return __builtin_nanf("");
  float x = fmaxf(xin, 1.17549435e-38f);
  uint32_t xb = __float_as_uint(x);
  int e_int = (int)(xb >> 23) - 0x7f;
  x = __uint_as_float((xb & 0x807fffffu) | 0x3f000000u);  // mantissa in [0.5,1)
  float e = __fadd_rn((float)e_int, 1.0f);
  bool mlt = x < 0.707106781186547524f;
  float tmp = mlt ? x : 0.0f;
  x = __fsub_rn(x, 1.0f);
  e = __fsub_rn(e, mlt ? 1.0f : 0.0f);
  x = __fadd_rn(x, tmp);
  float z = __fmul_rn(x, x);
  float y = 7.0376836292e-2f;
  y = __fadd_rn(__fmul_rn(y, x), -1.1514610310e-1f);
  y = __fadd_rn(__fmul_rn(y, x),  1.1676998740e-1f);
  y = __fadd_rn(__fmul_rn(y, x), -1.2420140846e-1f);
  y = __fadd_rn(__fmul_rn(y, x),  1.4249322787e-1f);
  y = __fadd_rn(__fmul_rn(y, x), -1.6668057665e-1f);
  y = __fadd_rn(__fmul_rn(y, x),  2.0000714765e-1f);
  y = __fadd_rn(__fmul_rn(y, x), -2.4999993993e-1f);
  y = __fadd_rn(__fmul_rn(y, x),  3.3333331174e-1f);
  y = __fmul_rn(y, x);
  y = __fmul_rn(y, z);
  y = __fadd_rn(y, __fmul_rn(e, -2.12194440e-4f));
  y = __fsub_rn(y, __fmul_rn(z, 0.5f));
  x = __fadd_rn(x, y);
  x = __fadd_rn(x, __fmul_rn(e, 0.693359375f));
  return x;
}

__device__ float cephes_expf(float xin) {
  float x = fminf(xin, 88.3762626647950f);
  x = fmaxf(x, -88.3762626647949f);
  float fx = __fadd_rn(__fmul_rn(x, 1.44269504088896341f), 0.5f);
  fx = floorf(fx);
  float tmp = __fmul_rn(fx, 0.693359375f);
  float z2  = __fmul_rn(fx, -2.12194440e-4f);
  x = __fsub_rn(x, tmp);
  x = __fsub_rn(x, z2);
  float z = __fmul_rn(x, x);
  float y = 1.9875691500e-4f;
  y = __fadd_rn(__fmul_rn(y, x), 1.3981999507e-3f);
  y = __fadd_rn(__fmul_rn(y, x), 8.3334519073e-3f);
  y = __fadd_rn(__fmul_rn(y, x), 4.1665795894e-2f);
  y = __fadd_rn(__fmul_rn(y, x), 1.6666665459e-1f);
  y = __fadd_rn(__fmul_rn(y, x), 5.0000001201e-1f);
  y = __fadd_rn(__fmul_rn(y, z), x);
  y = __fadd_rn(y, 1.0f);
  int n = (int)fx;
  float p2n = __uint_as_float((uint32_t)(n + 0x7f) << 23);
  return __fmul_rn(y, p2n);
}

__device__ __forceinline__ float xla_log1p(float x) {
  float for_small = __fmul_rn(__fadd_rn(__fmul_rn(-0.5f, x), 1.0f), x);
  float for_large = cephes_logf(__fadd_rn(x, 1.0f));
  return (fabsf(x) < 1e-4f) ? for_small : for_large;
}

__device__ float xla_erfinv_f32(float x) {
  float m = __fmul_rn(x, x);
  float w = -xla_log1p(-m);
  float ws = __fsub_rn(w, 2.5f);
  float ps = 2.81022636e-08f;
  ps = __fadd_rn(__fmul_rn(ps, ws), 3.43273939e-07f);
  ps = __fadd_rn(__fmul_rn(ps, ws), -3.5233877e-06f);
  ps = __fadd_rn(__fmul_rn(ps, ws), -4.39150654e-06f);
  ps = __fadd_rn(__fmul_rn(ps, ws), 0.00021858087f);
  ps = __fadd_rn(__fmul_rn(ps, ws), -0.00125372503f);
  ps = __fadd_rn(__fmul_rn(ps, ws), -0.00417768164f);
  ps = __fadd_rn(__fmul_rn(ps, ws), 0.246640727f);
  ps = __fadd_rn(__fmul_rn(ps, ws), 1.50140941f);
  float p = ps;
  if (__ballot(w >= 5.0f) != 0ull) {
    float wb = __fsub_rn(__fsqrt_rn(w), 3.0f);
    float pb = -0.000200214257f;
    pb = __fadd_rn(__fmul_rn(pb, wb), 0.000100950558f);
    pb = __fadd_rn(__fmul_rn(pb, wb), 0.00134934322f);
    pb = __fadd_rn(__fmul_rn(pb, wb), -0.00367342844f);
    pb = __fadd_rn(__fmul_rn(pb, wb), 0.00573950773f);
    pb = __fadd_rn(__fmul_rn(pb, wb), -0.0076224613f);
    pb = __fadd_rn(__fmul_rn(pb, wb), 0.00943887047f);
    pb = __fadd_rn(__fmul_rn(pb, wb), 1.00167406f);
    pb = __fadd_rn(__fmul_rn(pb, wb), 2.83297682f);
    p = (w < 5.0f) ? ps : pb;
  }
  return __fmul_rn(p, x);
}

__device__ __forceinline__ float normal_from_bits_exact(uint32_t bits) {
  float f = u01_from_bits(bits);
  float u = __fadd_rn(__fmul_rn(f, 2.0f), -0.99999994f);
  u = fmaxf(-0.99999994f, u);
  return __fmul_rn(1.4142135623730951f, xla_erfinv_f32(u));
}

__device__ float loggamma2555(uint2 K) {
  const float ONE3 = 1.0f / 3.0f;
  const float d_g  = __fsub_rn(255.5f, ONE3);
  const float c_g  = __fdiv_rn(ONE3, __fsqrt_rn(d_g));

  uint2 key = foldkey(K, 0u);   // key, subkey = split(key); u_boost unused

  float X = 0.0f, V = 1.0f, U = 2.0f;
  for (;;) {
    float sq = __fsub_rn(1.0f, __fmul_rn(0.0331f, __fmul_rn(X, X)));
    bool c1 = (U >= sq);
    bool c2 = false;
    if (c1) {
      float rhs = __fadd_rn(__fmul_rn(X, 0.5f),
                            __fmul_rn(d_g, __fadd_rn(__fsub_rn(1.0f, V),
                                                     cephes_logf(V))));
      c2 = (cephes_logf(U) >= rhs);
    }
    if (!(c1 && c2)) break;

    uint2 nk   = foldkey(key, 0u);
    uint2 xkey = foldkey(key, 1u);
    uint2 Ukey = foldkey(key, 2u);
    key = nk;
    float x, v;
    do {
      uint2 nxk  = foldkey(xkey, 0u);
      uint2 nsub = foldkey(xkey, 1u);
      xkey = nxk;
      x = normal_from_bits_exact(xbits(nsub, 0u));
      v = __fadd_rn(1.0f, __fmul_rn(x, c_g));
    } while (v <= 0.0f);
    X = __fmul_rn(x, x);
    V = __fmul_rn(__fmul_rn(v, v), v);
    U = u01_from_bits(xbits(Ukey, 0u));
  }
  return __fadd_rn(__fadd_rn(cephes_logf(d_g), cephes_logf(V)), 0.0f);
}

// ---------------------------------------------------------------------------
// FAST PATH (K2 only) — sqrt(2)*erfinv(u) via HW v_log_f32 + fused fma poly.
// Error ~1e-6 absolute; tangential normals feed no rejection decision and the
// output error budget is ~3.6e-3. sqrt(2) is folded into the coefficients at
// compile time (float constant folding).
// ---------------------------------------------------------------------------
#define SQ2 1.41421356237309515f
__device__ __forceinline__ float fast_normal_sqrt2(uint32_t bits) {
  float f = u01_from_bits(bits);
  float u = fmaf(f, 2.0f, -0.99999994f);
  float m = u * u;
  float w = __log2f(1.0f - m) * (-0.69314718055994531f);   // -ln(1-m)
  float ws = w - 2.5f;
  float p = 2.81022636e-08f * SQ2;
  p = fmaf(p, ws, 3.43273939e-07f * SQ2);
  p = fmaf(p, ws, -3.5233877e-06f * SQ2);
  p = fmaf(p, ws, -4.39150654e-06f * SQ2);
  p = fmaf(p, ws, 0.00021858087f * SQ2);
  p = fmaf(p, ws, -0.00125372503f * SQ2);
  p = fmaf(p, ws, -0.00417768164f * SQ2);
  p = fmaf(p, ws, 0.246640727f * SQ2);
  p = fmaf(p, ws, 1.50140941f * SQ2);
  if (__ballot(w >= 5.0f) != 0ull) {           // ~20% of waves, wave-uniform
    float wb = __fsqrt_rn(w) - 3.0f;
    float pb = -0.000200214257f * SQ2;
    pb = fmaf(pb, wb, 0.000100950558f * SQ2);
    pb = fmaf(pb, wb, 0.00134934322f * SQ2);
    pb = fmaf(pb, wb, -0.00367342844f * SQ2);
    pb = fmaf(pb, wb, 0.00573950773f * SQ2);
    pb = fmaf(pb, wb, -0.0076224613f * SQ2);
    pb = fmaf(pb, wb, 0.00943887047f * SQ2);
    pb = fmaf(pb, wb, 1.00167406f * SQ2);
    pb = fmaf(pb, wb, 2.83297682f * SQ2);
    p = (w < 5.0f) ? p : pb;
  }
  return p * u;
}

__device__ __forceinline__ float wave_reduce64(float v) {
  for (int off = 32; off >= 1; off >>= 1) v += __shfl_xor(v, off, 64);
  return v;
}

// ============================================================================
// K1: one lane-pair per row; serial Wood rejection with early exit.
// Fully exact path. w -> out[r*512].
// ============================================================================
__global__ void __launch_bounds__(256)
vmf_w_kernel(const float* __restrict__ scale, float* __restrict__ out, int B) {
  const int gt = blockIdx.x * 256 + threadIdx.x;
  const int r = gt >> 1;
  const int parity = gt & 1;
  if (r >= B) return;

  const uint2 key42 = make_uint2(0u, 42u);
  const float kappa = scale[r];

  const float c_ = __fsqrt_rn(__fadd_rn(__fmul_rn(4.0f, __fmul_rn(kappa, kappa)),
                                        261121.0f));
  const float b_app  = __fdiv_rn(511.0f, __fmul_rn(4.0f, kappa));
  const float b_true = __fdiv_rn(__fadd_rn(__fmul_rn(-2.0f, kappa), c_), 511.0f);
  float s_ = __fsub_rn(kappa, 10.0f);
  s_ = fminf(fmaxf(s_, 0.0f), 1.0f);
  const float b = __fadd_rn(__fmul_rn(b_app, s_),
                            __fmul_rn(b_true, __fsub_rn(1.0f, s_)));
  const float a = __fdiv_rn(__fadd_rn(__fadd_rn(511.0f, __fmul_rn(2.0f, kappa)), c_),
                            4.0f);
  const float log511 = cephes_logf(511.0f);
  const float dconst = __fsub_rn(
      __fdiv_rn(__fmul_rn(__fmul_rn(4.0f, a), b), __fadd_rn(1.0f, b)),
      __fmul_rn(511.0f, log511));

  const uint2 kw = foldkey(key42, 0u);

  float w_val = 0.0f;
  for (int i = 0; i < 50; ++i) {
    uint2 ki = foldkey(kw, (uint32_t)i);
    uint2 kb = foldkey(ki, 0u);
    uint2 ku = foldkey(ki, 1u);
    uint2 kg = foldkey(kb, (uint32_t)parity);    // key_a (p=0) / key_b (p=1)
    float lg_self  = loggamma2555(foldkey(kg, (uint32_t)r));
    float lg_other = __shfl_xor(lg_self, 1, 64);
    float lga = parity ? lg_other : lg_self;
    float lgb = parity ? lg_self  : lg_other;
    float lm  = fmaxf(lga, lgb);
    float gas = cephes_expf(__fsub_rn(lga, lm));
    float gbs = cephes_expf(__fsub_rn(lgb, lm));
    float e_  = __fdiv_rn(gas, __fadd_rn(gas, gbs));
    float uu  = u01_from_bits(xbits(ku, (uint32_t)r));

    float denom = __fsub_rn(1.0f, __fmul_rn(__fsub_rn(1.0f, b), e_));
    float w_ = __fdiv_rn(__fsub_rn(1.0f, __fmul_rn(__fadd_rn(1.0f, b), e_)), denom);
    float tt  = __fdiv_rn(__fmul_rn(__fmul_rn(2.0f, a), b), denom);
    float lhs = __fadd_rn(__fsub_rn(__fmul_rn(511.0f, cephes_logf(tt)), tt), dconst);
    if (lhs > cephes_logf(uu)) { w_val = w_; break; }   // first accept wins
  }
  if (parity == 0) out[(size_t)r * 512] = w_val;
}

// ============================================================================
// K2: 256 threads per row; tangential normals (fast path) + Householder.
// Reads w from out[r*512] (written by K1) before overwriting the row.
// ============================================================================
__global__ void __launch_bounds__(256)
vmf_tan_kernel(const float* __restrict__ loc, float* __restrict__ out, int B) {
  const int r = blockIdx.x;
  const int t = threadIdx.x;
  const int lane = t & 63, wid = t >> 6;

  __shared__ float s_part[3][4];

  const float w = out[(size_t)r * 512];          // from K1

  const uint2 key42 = make_uint2(0u, 42u);
  const uint2 kv = foldkey(key42, 1u);           // compile-time constant fold
  const int cA = t, cB = t + 256;
  const float lA = loc[(size_t)r * 512 + cA];
  const float lB = loc[(size_t)r * 512 + cB];
  const float uhA = (cA == 0) ? (1.0f - lA) : (-lA);
  const float uhB = -lB;
  float vfA = 0.0f;
  if (cA >= 1) vfA = fast_normal_sqrt2(xbits(kv, (uint32_t)(r * 512 + cA)));
  float vfB = fast_normal_sqrt2(xbits(kv, (uint32_t)(r * 512 + cB)));

  float rv = wave_reduce64(fmaf(vfA, vfA, vfB * vfB));
  float ru = wave_reduce64(fmaf(uhA, uhA, uhB * uhB));
  if (lane == 0) { s_part[0][wid] = rv; s_part[1][wid] = ru; }
  __syncthreads();
  const float SV = s_part[0][0] + s_part[0][1] + s_part[0][2] + s_part[0][3];
  const float SU = s_part[1][0] + s_part[1][1] + s_part[1][2] + s_part[1][3];

  const float inv_normv = __fdividef(1.0f, __fsqrt_rn(SV));
  const float inv_normu = __fdividef(1.0f, __fsqrt_rn(SU) + 1e-5f);
  const float fac = __fsqrt_rn(fmaxf(1e-10f, fmaf(-w, w, 1.0f)));

  const float xA = (cA == 0) ? w : fac * (vfA * inv_normv);
  const float xB = fac * (vfB * inv_normv);
  const float uuA = uhA * inv_normu;
  const float uuB = uhB * inv_normu;

  float rd = wave_reduce64(fmaf(xA, uuA, xB * uuB));
  if (lane == 0) s_part[2][wid] = rd;
  __syncthreads();
  const float DOT = s_part[2][0] + s_part[2][1] + s_part[2][2] + s_part[2][3];
  const float s2 = 2.0f * DOT;

  out[(size_t)r * 512 + cA] = fmaf(-s2, uuA, xA);
  out[(size_t)r * 512 + cB] = fmaf(-s2, uuB, xB);
}

extern "C" void kernel_launch(void* const* d_in, const int* in_sizes, int n_in,
                              void* d_out, int out_size, void* d_ws, size_t ws_size,
                              hipStream_t stream) {
  const float* loc   = (const float*)d_in[0];
  const float* scale = (const float*)d_in[1];
  float* out = (float*)d_out;
  const int B = in_sizes[1];     // scale is (B,1); loc is (B,512)
  const int g1 = (2 * B + 255) / 256;
  hipLaunchKernelGGL(vmf_w_kernel, dim3(g1), dim3(256), 0, stream, scale, out, B);
  hipLaunchKernelGGL(vmf_tan_kernel, dim3(B), dim3(256), 0, stream, loc, out, B);
}

// Round 5
// 50.242 us; speedup vs baseline: 3.9865x; 1.1849x over previous
//
#include <hip/hip_runtime.h>
#include <stdint.h>
#include <math.h>

// ============================================================================
// Bit-exact-where-it-matters re-implementation of the JAX (XLA:CPU) sampler.
//
// RNG mode: jax_threefry_partitionable = True.
//   split(key, n)[i]      = threefry2x32(key, (0, i))          (both words)
//   random_bits32 elem i  = v0 ^ v1 of threefry2x32(key, (0, i))
//
// K1 (w-path): FULL bit-exactness (Cephes log/exp, unfused rn ops) — the
//   rejection decisions amplify perturbations by x255/x511; one ulp can flip
//   an accept (~0.01..0.05 output error). DO NOT touch this path.
// K2 (tangential): decision-free; error budget ~3.6e-3. One WAVE per row,
//   8 elems/thread (float4 IO), analytic SU/DOT (no LDS, no barriers),
//   HW v_log_f32 + fused-fma erfinv.
// ============================================================================

__device__ __forceinline__ uint2 tf2(uint2 k, uint32_t c0, uint32_t c1) {
  uint32_t ks0 = k.x, ks1 = k.y, ks2 = k.x ^ k.y ^ 0x1BD11BDAu;
  uint32_t x0 = c0 + ks0, x1 = c1 + ks1;
#define TFR(r) { x0 += x1; x1 = __builtin_rotateleft32(x1, r); x1 ^= x0; }
  TFR(13) TFR(15) TFR(26) TFR(6)   x0 += ks1; x1 += ks2 + 1u;
  TFR(17) TFR(29) TFR(16) TFR(24)  x0 += ks2; x1 += ks0 + 2u;
  TFR(13) TFR(15) TFR(26) TFR(6)   x0 += ks0; x1 += ks1 + 3u;
  TFR(17) TFR(29) TFR(16) TFR(24)  x0 += ks1; x1 += ks2 + 4u;
  TFR(13) TFR(15) TFR(26) TFR(6)   x0 += ks2; x1 += ks0 + 5u;
#undef TFR
  return make_uint2(x0, x1);
}

__device__ __forceinline__ uint2 foldkey(uint2 k, uint32_t i) { return tf2(k, 0u, i); }
__device__ __forceinline__ uint32_t xbits(uint2 k, uint32_t i) {
  uint2 r = tf2(k, 0u, i);
  return r.x ^ r.y;
}

__device__ __forceinline__ float u01_from_bits(uint32_t bits) {
  return __fsub_rn(__uint_as_float((bits >> 9) | 0x3f800000u), 1.0f);
}

// ---------------------------------------------------------------------------
// EXACT PATH (K1 only) — XLA:CPU Cephes log/exp, XLA log1p/erfinv, rn ops.
// ---------------------------------------------------------------------------
__device__ float cephes_logf(float xin) {
  if (xin == 0.0f) return -__builtin_inff();
  if (xin < 0.0f)  return __builtin_nanf("");
  float x = fmaxf(xin, 1.17549435e-38f);
  uint32_t xb = __float_as_uint(x);
  int e_int = (int)(xb >> 23) - 0x7f;
  x = __uint_as_float((xb & 0x807fffffu) | 0x3f000000u);  // mantissa in [0.5,1)
  float e = __fadd_rn((float)e_int, 1.0f);
  bool mlt = x < 0.707106781186547524f;
  float tmp = mlt ? x : 0.0f;
  x = __fsub_rn(x, 1.0f);
  e = __fsub_rn(e, mlt ? 1.0f : 0.0f);
  x = __fadd_rn(x, tmp);
  float z = __fmul_rn(x, x);
  float y = 7.0376836292e-2f;
  y = __fadd_rn(__fmul_rn(y, x), -1.1514610310e-1f);
  y = __fadd_rn(__fmul_rn(y, x),  1.1676998740e-1f);
  y = __fadd_rn(__fmul_rn(y, x), -1.2420140846e-1f);
  y = __fadd_rn(__fmul_rn(y, x),  1.4249322787e-1f);
  y = __fadd_rn(__fmul_rn(y, x), -1.6668057665e-1f);
  y = __fadd_rn(__fmul_rn(y, x),  2.0000714765e-1f);
  y = __fadd_rn(__fmul_rn(y, x), -2.4999993993e-1f);
  y = __fadd_rn(__fmul_rn(y, x),  3.3333331174e-1f);
  y = __fmul_rn(y, x);
  y = __fmul_rn(y, z);
  y = __fadd_rn(y, __fmul_rn(e, -2.12194440e-4f));
  y = __fsub_rn(y, __fmul_rn(z, 0.5f));
  x = __fadd_rn(x, y);
  x = __fadd_rn(x, __fmul_rn(e, 0.693359375f));
  return x;
}

__device__ float cephes_expf(float xin) {
  float x = fminf(xin, 88.3762626647950f);
  x = fmaxf(x, -88.3762626647949f);
  float fx = __fadd_rn(__fmul_rn(x, 1.44269504088896341f), 0.5f);
  fx = floorf(fx);
  float tmp = __fmul_rn(fx, 0.693359375f);
  float z2  = __fmul_rn(fx, -2.12194440e-4f);
  x = __fsub_rn(x, tmp);
  x = __fsub_rn(x, z2);
  float z = __fmul_rn(x, x);
  float y = 1.9875691500e-4f;
  y = __fadd_rn(__fmul_rn(y, x), 1.3981999507e-3f);
  y = __fadd_rn(__fmul_rn(y, x), 8.3334519073e-3f);
  y = __fadd_rn(__fmul_rn(y, x), 4.1665795894e-2f);
  y = __fadd_rn(__fmul_rn(y, x), 1.6666665459e-1f);
  y = __fadd_rn(__fmul_rn(y, x), 5.0000001201e-1f);
  y = __fadd_rn(__fmul_rn(y, z), x);
  y = __fadd_rn(y, 1.0f);
  int n = (int)fx;
  float p2n = __uint_as_float((uint32_t)(n + 0x7f) << 23);
  return __fmul_rn(y, p2n);
}

__device__ __forceinline__ float xla_log1p(float x) {
  float for_small = __fmul_rn(__fadd_rn(__fmul_rn(-0.5f, x), 1.0f), x);
  float for_large = cephes_logf(__fadd_rn(x, 1.0f));
  return (fabsf(x) < 1e-4f) ? for_small : for_large;
}

__device__ float xla_erfinv_f32(float x) {
  float m = __fmul_rn(x, x);
  float w = -xla_log1p(-m);
  float ws = __fsub_rn(w, 2.5f);
  float ps = 2.81022636e-08f;
  ps = __fadd_rn(__fmul_rn(ps, ws), 3.43273939e-07f);
  ps = __fadd_rn(__fmul_rn(ps, ws), -3.5233877e-06f);
  ps = __fadd_rn(__fmul_rn(ps, ws), -4.39150654e-06f);
  ps = __fadd_rn(__fmul_rn(ps, ws), 0.00021858087f);
  ps = __fadd_rn(__fmul_rn(ps, ws), -0.00125372503f);
  ps = __fadd_rn(__fmul_rn(ps, ws), -0.00417768164f);
  ps = __fadd_rn(__fmul_rn(ps, ws), 0.246640727f);
  ps = __fadd_rn(__fmul_rn(ps, ws), 1.50140941f);
  float p = ps;
  if (__ballot(w >= 5.0f) != 0ull) {
    float wb = __fsub_rn(__fsqrt_rn(w), 3.0f);
    float pb = -0.000200214257f;
    pb = __fadd_rn(__fmul_rn(pb, wb), 0.000100950558f);
    pb = __fadd_rn(__fmul_rn(pb, wb), 0.00134934322f);
    pb = __fadd_rn(__fmul_rn(pb, wb), -0.00367342844f);
    pb = __fadd_rn(__fmul_rn(pb, wb), 0.00573950773f);
    pb = __fadd_rn(__fmul_rn(pb, wb), -0.0076224613f);
    pb = __fadd_rn(__fmul_rn(pb, wb), 0.00943887047f);
    pb = __fadd_rn(__fmul_rn(pb, wb), 1.00167406f);
    pb = __fadd_rn(__fmul_rn(pb, wb), 2.83297682f);
    p = (w < 5.0f) ? ps : pb;
  }
  return __fmul_rn(p, x);
}

__device__ __forceinline__ float normal_from_bits_exact(uint32_t bits) {
  float f = u01_from_bits(bits);
  float u = __fadd_rn(__fmul_rn(f, 2.0f), -0.99999994f);
  u = fmaxf(-0.99999994f, u);
  return __fmul_rn(1.4142135623730951f, xla_erfinv_f32(u));
}

__device__ float loggamma2555(uint2 K) {
  const float ONE3 = 1.0f / 3.0f;
  const float d_g  = __fsub_rn(255.5f, ONE3);
  const float c_g  = __fdiv_rn(ONE3, __fsqrt_rn(d_g));

  uint2 key = foldkey(K, 0u);   // key, subkey = split(key); u_boost unused

  float X = 0.0f, V = 1.0f, U = 2.0f;
  for (;;) {
    float sq = __fsub_rn(1.0f, __fmul_rn(0.0331f, __fmul_rn(X, X)));
    bool c1 = (U >= sq);
    bool c2 = false;
    if (c1) {
      float rhs = __fadd_rn(__fmul_rn(X, 0.5f),
                            __fmul_rn(d_g, __fadd_rn(__fsub_rn(1.0f, V),
                                                     cephes_logf(V))));
      c2 = (cephes_logf(U) >= rhs);
    }
    if (!(c1 && c2)) break;

    uint2 nk   = foldkey(key, 0u);
    uint2 xkey = foldkey(key, 1u);
    uint2 Ukey = foldkey(key, 2u);
    key = nk;
    float x, v;
    do {
      uint2 nxk  = foldkey(xkey, 0u);
      uint2 nsub = foldkey(xkey, 1u);
      xkey = nxk;
      x = normal_from_bits_exact(xbits(nsub, 0u));
      v = __fadd_rn(1.0f, __fmul_rn(x, c_g));
    } while (v <= 0.0f);
    X = __fmul_rn(x, x);
    V = __fmul_rn(__fmul_rn(v, v), v);
    U = u01_from_bits(xbits(Ukey, 0u));
  }
  return __fadd_rn(__fadd_rn(cephes_logf(d_g), cephes_logf(V)), 0.0f);
}

// ---------------------------------------------------------------------------
// FAST PATH (K2 only) — sqrt(2)*erfinv(u) via HW v_log_f32 + fused fma poly.
// u = 2*m - 3  (m in [1,2)) is exact and within 6e-8 of the reference's
// fmaf(f,2,-0.99999994); clamp keeps bits==0 off the singularity.
// ---------------------------------------------------------------------------
#define SQ2 1.41421356237309515f
__device__ __forceinline__ float fast_normal_sqrt2(uint32_t bits) {
  float mm = __uint_as_float((bits >> 9) | 0x3f800000u);   // [1,2)
  float u = fmaf(2.0f, mm, -3.0f);                          // [-1,1)
  u = fmaxf(-0.99999994f, u);
  float w = __log2f(fmaf(-u, u, 1.0f)) * (-0.69314718055994531f);  // -ln(1-u^2)
  float ws = w - 2.5f;
  float p = 2.81022636e-08f * SQ2;
  p = fmaf(p, ws, 3.43273939e-07f * SQ2);
  p = fmaf(p, ws, -3.5233877e-06f * SQ2);
  p = fmaf(p, ws, -4.39150654e-06f * SQ2);
  p = fmaf(p, ws, 0.00021858087f * SQ2);
  p = fmaf(p, ws, -0.00125372503f * SQ2);
  p = fmaf(p, ws, -0.00417768164f * SQ2);
  p = fmaf(p, ws, 0.246640727f * SQ2);
  p = fmaf(p, ws, 1.50140941f * SQ2);
  if (__ballot(w >= 5.0f) != 0ull) {           // wave-uniform rare branch
    float wb = __fsqrt_rn(w) - 3.0f;
    float pb = -0.000200214257f * SQ2;
    pb = fmaf(pb, wb, 0.000100950558f * SQ2);
    pb = fmaf(pb, wb, 0.00134934322f * SQ2);
    pb = fmaf(pb, wb, -0.00367342844f * SQ2);
    pb = fmaf(pb, wb, 0.00573950773f * SQ2);
    pb = fmaf(pb, wb, -0.0076224613f * SQ2);
    pb = fmaf(pb, wb, 0.00943887047f * SQ2);
    pb = fmaf(pb, wb, 1.00167406f * SQ2);
    pb = fmaf(pb, wb, 2.83297682f * SQ2);
    p = (w < 5.0f) ? p : pb;
  }
  return p * u;
}

// ============================================================================
// K1: one lane-pair per row; serial Wood rejection with early exit.
// Fully exact path. w -> out[r*512].  (UNCHANGED from round 3.)
// ============================================================================
__global__ void __launch_bounds__(256)
vmf_w_kernel(const float* __restrict__ scale, float* __restrict__ out, int B) {
  const int gt = blockIdx.x * 256 + threadIdx.x;
  const int r = gt >> 1;
  const int parity = gt & 1;
  if (r >= B) return;

  const uint2 key42 = make_uint2(0u, 42u);
  const float kappa = scale[r];

  const float c_ = __fsqrt_rn(__fadd_rn(__fmul_rn(4.0f, __fmul_rn(kappa, kappa)),
                                        261121.0f));
  const float b_app  = __fdiv_rn(511.0f, __fmul_rn(4.0f, kappa));
  const float b_true = __fdiv_rn(__fadd_rn(__fmul_rn(-2.0f, kappa), c_), 511.0f);
  float s_ = __fsub_rn(kappa, 10.0f);
  s_ = fminf(fmaxf(s_, 0.0f), 1.0f);
  const float b = __fadd_rn(__fmul_rn(b_app, s_),
                            __fmul_rn(b_true, __fsub_rn(1.0f, s_)));
  const float a = __fdiv_rn(__fadd_rn(__fadd_rn(511.0f, __fmul_rn(2.0f, kappa)), c_),
                            4.0f);
  const float log511 = cephes_logf(511.0f);
  const float dconst = __fsub_rn(
      __fdiv_rn(__fmul_rn(__fmul_rn(4.0f, a), b), __fadd_rn(1.0f, b)),
      __fmul_rn(511.0f, log511));

  const uint2 kw = foldkey(key42, 0u);

  float w_val = 0.0f;
  for (int i = 0; i < 50; ++i) {
    uint2 ki = foldkey(kw, (uint32_t)i);
    uint2 kb = foldkey(ki, 0u);
    uint2 ku = foldkey(ki, 1u);
    uint2 kg = foldkey(kb, (uint32_t)parity);    // key_a (p=0) / key_b (p=1)
    float lg_self  = loggamma2555(foldkey(kg, (uint32_t)r));
    float lg_other = __shfl_xor(lg_self, 1, 64);
    float lga = parity ? lg_other : lg_self;
    float lgb = parity ? lg_self  : lg_other;
    float lm  = fmaxf(lga, lgb);
    float gas = cephes_expf(__fsub_rn(lga, lm));
    float gbs = cephes_expf(__fsub_rn(lgb, lm));
    float e_  = __fdiv_rn(gas, __fadd_rn(gas, gbs));
    float uu  = u01_from_bits(xbits(ku, (uint32_t)r));

    float denom = __fsub_rn(1.0f, __fmul_rn(__fsub_rn(1.0f, b), e_));
    float w_ = __fdiv_rn(__fsub_rn(1.0f, __fmul_rn(__fadd_rn(1.0f, b), e_)), denom);
    float tt  = __fdiv_rn(__fmul_rn(__fmul_rn(2.0f, a), b), denom);
    float lhs = __fadd_rn(__fsub_rn(__fmul_rn(511.0f, cephes_logf(tt)), tt), dconst);
    if (lhs > cephes_logf(uu)) { w_val = w_; break; }   // first accept wins
  }
  if (parity == 0) out[(size_t)r * 512] = w_val;
}

// ============================================================================
// K2: ONE WAVE PER ROW (4 rows / 256-thr block). 8 elems/thread via float4.
// No LDS, no barriers. Analytic identities (error ~1e-6, budget 3.6e-3):
//   SU  = ||e1-loc||^2 = 2*(1-loc0)                  (loc is unit-norm)
//   DOT = inv_normu * (w*uh0 - h*T),  T = sum vf_i*loc_i  (same pass as SV)
//   z_i = h*vf_i + g*loc_i (i>=1),  z_0 = w - g*uh0,  g = 2*DOT*inv_normu
// ============================================================================
__global__ void __launch_bounds__(256)
vmf_tan_kernel(const float* __restrict__ loc, float* __restrict__ out, int B) {
  const int t = threadIdx.x;
  const int lane = t & 63, wid = t >> 6;
  const int r = blockIdx.x * 4 + wid;
  if (r >= B) return;

  const float w = out[(size_t)r * 512];          // from K1 (read before stores)

  const uint2 key42 = make_uint2(0u, 42u);
  const uint2 kv = foldkey(key42, 1u);           // compile-time constant fold

  const float4* locv = (const float4*)(loc + (size_t)r * 512);
  float4*       outv = (float4*)(out + (size_t)r * 512);

  const float4 l0 = locv[lane];                  // cols 4*lane .. 4*lane+3
  const float4 l1 = locv[lane + 64];             // cols 256+4*lane ..

  const uint32_t cb = (uint32_t)(r * 512 + lane * 4);

  // 8 independent threefry chains -> high ILP
  float vf0 = fast_normal_sqrt2(xbits(kv, cb + 0u));
  float vf1 = fast_normal_sqrt2(xbits(kv, cb + 1u));
  float vf2 = fast_normal_sqrt2(xbits(kv, cb + 2u));
  float vf3 = fast_normal_sqrt2(xbits(kv, cb + 3u));
  float vf4 = fast_normal_sqrt2(xbits(kv, cb + 256u));
  float vf5 = fast_normal_sqrt2(xbits(kv, cb + 257u));
  float vf6 = fast_normal_sqrt2(xbits(kv, cb + 258u));
  float vf7 = fast_normal_sqrt2(xbits(kv, cb + 259u));
  if (lane == 0) vf0 = 0.0f;                     // col 0 excluded from v

  // single-pass partials: SV = sum vf^2, T = sum vf*loc
  float sv = vf0 * vf0;
  sv = fmaf(vf1, vf1, sv); sv = fmaf(vf2, vf2, sv); sv = fmaf(vf3, vf3, sv);
  sv = fmaf(vf4, vf4, sv); sv = fmaf(vf5, vf5, sv); sv = fmaf(vf6, vf6, sv);
  sv = fmaf(vf7, vf7, sv);
  float tt = vf0 * l0.x;
  tt = fmaf(vf1, l0.y, tt); tt = fmaf(vf2, l0.z, tt); tt = fmaf(vf3, l0.w, tt);
  tt = fmaf(vf4, l1.x, tt); tt = fmaf(vf5, l1.y, tt); tt = fmaf(vf6, l1.z, tt);
  tt = fmaf(vf7, l1.w, tt);

  // interleaved wave reduction (two independent chains)
#pragma unroll
  for (int off = 32; off >= 1; off >>= 1) {
    sv += __shfl_xor(sv, off, 64);
    tt += __shfl_xor(tt, off, 64);
  }

  const float loc0 = __shfl(l0.x, 0, 64);
  const float uh0  = 1.0f - loc0;
  const float SU   = 2.0f * uh0;                 // == ||e1-loc||^2 (unit loc)

  const float inv_normu = __fdividef(1.0f, __fsqrt_rn(SU) + 1e-5f);
  const float inv_normv = __fdividef(1.0f, __fsqrt_rn(sv));
  const float fac = __fsqrt_rn(fmaxf(1e-10f, fmaf(-w, w, 1.0f)));
  const float h = fac * inv_normv;
  const float DOT = inv_normu * fmaf(w, uh0, -(h * tt));
  const float g = 2.0f * DOT * inv_normu;

  float4 o0, o1;
  o0.x = (lane == 0) ? fmaf(-g, uh0, w) : fmaf(h, vf0, g * l0.x);
  o0.y = fmaf(h, vf1, g * l0.y);
  o0.z = fmaf(h, vf2, g * l0.z);
  o0.w = fmaf(h, vf3, g * l0.w);
  o1.x = fmaf(h, vf4, g * l1.x);
  o1.y = fmaf(h, vf5, g * l1.y);
  o1.z = fmaf(h, vf6, g * l1.z);
  o1.w = fmaf(h, vf7, g * l1.w);
  outv[lane]      = o0;
  outv[lane + 64] = o1;
}

extern "C" void kernel_launch(void* const* d_in, const int* in_sizes, int n_in,
                              void* d_out, int out_size, void* d_ws, size_t ws_size,
                              hipStream_t stream) {
  const float* loc   = (const float*)d_in[0];
  const float* scale = (const float*)d_in[1];
  float* out = (float*)d_out;
  const int B = in_sizes[1];     // scale is (B,1); loc is (B,512)
  const int g1 = (2 * B + 255) / 256;
  const int g2 = (B + 3) / 4;
  hipLaunchKernelGGL(vmf_w_kernel, dim3(g1), dim3(256), 0, stream, scale, out, B);
  hipLaunchKernelGGL(vmf_tan_kernel, dim3(g2), dim3(256), 0, stream, loc, out, B);
}